// Round 13
// baseline (113.641 us; speedup 1.0000x reference)
//
#include <hip/hip_runtime.h>
#include <math.h>

// SS2D: B=1, D=96, H=W=96, L=9216, K=4, N=16, R=6
constexpr int cD = 96, cL = 9216, cK = 4;
constexpr int CL = 36, NCH = 256;       // 256 chunks of 36 per sequence
constexpr long cDL = (long)cD * cL;
constexpr float LOG2E = 1.44269504088896f;

// ws float offsets (~48 MB)
constexpr long OFF_XT    = 0;                       // [96][9216]
constexpr long OFF_DELTA = OFF_XT    + cDL;         // [K][96][9216] d-major
constexpr long OFF_BC    = OFF_DELTA + 4L*cDL;      // [K][36][256][32] j-major, B|C packed
constexpr long OFF_Y     = OFF_BC    + 4L*cL*32;    // [K][96][9216] scan-raster
constexpr long OFF_YT    = OFF_Y     + 4L*cDL;      // [2][96][9216] Y1T,Y3T

__device__ __forceinline__ float4 a2prep(float4 v) {
    return make_float4(-LOG2E * exp2f(LOG2E * v.x), -LOG2E * exp2f(LOG2E * v.y),
                       -LOG2E * exp2f(LOG2E * v.z), -LOG2E * exp2f(LOG2E * v.w));
}
template<int C>
__device__ __forceinline__ float qperm(float v) {
    return __int_as_float(__builtin_amdgcn_mov_dpp(__float_as_int(v), C, 0xf, 0xf, true));
}

// ---- kT: xT[d][w*96+h] = x[d][h*96+w] --------------------------------------
__global__ __launch_bounds__(256) void kT(const float* __restrict__ x,
                                          float* __restrict__ xT) {
    __shared__ float t[32][33];
    const int h0 = blockIdx.x * 32, w0 = blockIdx.y * 32, d = blockIdx.z;
    const float* xd = x + (long)d * cL;
    float* xtd = xT + (long)d * cL;
    for (int o = threadIdx.x; o < 1024; o += 256) {
        int i = o >> 5, j = o & 31;
        t[i][j] = xd[(h0 + i) * 96 + w0 + j];
    }
    __syncthreads();
    for (int o = threadIdx.x; o < 1024; o += 256) {
        int i = o >> 5, j = o & 31;
        xtd[(w0 + i) * 96 + h0 + j] = t[j][i];
    }
}

// ---- kA: G = W_k @ src_k; delta[k][d][p], BC[k][36][256][32] ---------------
__global__ __launch_bounds__(256) void kA(const float* __restrict__ x,
                                          const float* __restrict__ xT,
                                          const float* __restrict__ xpw,
                                          const float* __restrict__ dtw,
                                          const float* __restrict__ dtb,
                                          float* __restrict__ delta,
                                          float* __restrict__ BC) {
    __shared__ float xs[96][64];
    __shared__ float xdbl[38][65];
    __shared__ float dtw_l[96 * 6];
    __shared__ float dtb_l[96];
    const int p0 = blockIdx.x * 64;
    const int k  = blockIdx.y;
    const int tid = threadIdx.x;
    const float* src = (k & 1) ? xT : x;

    for (int o = tid; o < 96 * 64; o += 256) {
        int dd = o >> 6, pp = o & 63;
        xs[dd][pp] = src[(long)dd * cL + p0 + pp];
    }
    for (int o = tid; o < 96 * 6; o += 256) dtw_l[o] = dtw[k * 96 * 6 + o];
    if (tid < 96) dtb_l[tid] = dtb[k * 96 + tid];
    __syncthreads();

    const int lane = tid & 63;
    const int c0 = __builtin_amdgcn_readfirstlane((tid >> 6) * 10);
    const float* wk = xpw + (long)k * 38 * 96;
    float acc[10];
    #pragma unroll
    for (int i = 0; i < 10; ++i) acc[i] = 0.f;
    #pragma unroll 4
    for (int dd = 0; dd < 96; ++dd) {
        float xv = xs[dd][lane];
        #pragma unroll
        for (int i = 0; i < 10; ++i) {
            int c = c0 + i; c = c > 37 ? 37 : c;
            acc[i] = fmaf(xv, wk[c * 96 + dd], acc[i]);
        }
    }
    #pragma unroll
    for (int i = 0; i < 10; ++i) {
        int c = c0 + i; c = c > 37 ? 37 : c;
        xdbl[c][lane] = acc[i];
    }
    __syncthreads();

    // BC scan-chunk-major: q = scan index, ch = q/36, j = q%36; B | C packed
    for (int o = tid; o < 64 * 16; o += 256) {
        int n = o & 15, pp = o >> 4;
        int P = p0 + pp;
        int q = (k < 2) ? P : (9215 - P);
        int ch = q / 36, j = q - ch * 36;
        long idx = (((long)k * 36 + j) * 256 + ch) * 32 + n;
        BC[idx]      = xdbl[6 + n][pp];
        BC[idx + 16] = xdbl[22 + n][pp];
    }
    for (int o = tid; o < 96 * 64; o += 256) {
        int dd = o >> 6, pp = o & 63;
        float s = dtb_l[dd];
        #pragma unroll
        for (int r = 0; r < 6; ++r) s = fmaf(xdbl[r][pp], dtw_l[dd * 6 + r], s);
        float sp = fmaxf(s, 0.f) + __logf(1.f + __expf(-fabsf(s)));
        delta[((long)(k * 96 + dd)) * cL + p0 + pp] = sp;
    }
}

// ---- kS: fused two-pass scan; 1024 thr = 256 quads; y in scan raster -------
__global__ __launch_bounds__(1024, 2) void kS(const float* __restrict__ x,
                                              const float* __restrict__ xT,
                                              const float* __restrict__ delta,
                                              const float* __restrict__ BC,
                                              const float* __restrict__ Alog,
                                              const float* __restrict__ Dsv,
                                              float* __restrict__ y) {
    __shared__ float lp[NCH][16];        // 16 KB (rows reused as gpf)
    __shared__ float ls[NCH][16];        // 16 KB
    float* gpf = &lp[0][0];
    const int tid = threadIdx.x;
    const int seq = blockIdx.x;                    // k*96+d
    const int k = seq / 96, d = seq % 96, rev = k >> 1;
    const int n0 = (tid & 3) * 4, ch = tid >> 2;   // ch in [0,256)
    const int r = tid & 3;
    const int q0 = rev ? (9215 - ch * CL) : ch * CL;

    const float4 a2 = a2prep(*(const float4*)(Alog + (long)seq * 16 + n0));
    const float Dv = Dsv[seq];
    const float* dB = delta + (long)seq * cL + q0;
    const float* xB = ((k & 1) ? xT : x) + (long)d * cL + q0;
    const float* bcB = BC + (long)k * cL * 32 + (long)ch * 32 + n0;

    // ---- pass 1: chunk summary ----
    float4 h = make_float4(0.f, 0.f, 0.f, 0.f);
    float sdl = 0.f;
#define S1(DL, XV, OFF) { \
        float4 B = *(const float4*)(bcB + (OFF) * 8192); \
        float t = (DL) * (XV); sdl += (DL); \
        h.x = fmaf(exp2f((DL)*a2.x), h.x, t*B.x); \
        h.y = fmaf(exp2f((DL)*a2.y), h.y, t*B.y); \
        h.z = fmaf(exp2f((DL)*a2.z), h.z, t*B.z); \
        h.w = fmaf(exp2f((DL)*a2.w), h.w, t*B.w); }
    if (!rev) {
        #pragma unroll
        for (int g = 0; g < 9; ++g) {
            float4 d4 = *(const float4*)(dB + 4*g);
            float4 x4 = *(const float4*)(xB + 4*g);
            S1(d4.x, x4.x, 4*g)   S1(d4.y, x4.y, 4*g+1)
            S1(d4.z, x4.z, 4*g+2) S1(d4.w, x4.w, 4*g+3)
        }
    } else {
        #pragma unroll
        for (int g = 0; g < 9; ++g) {
            float4 d4 = *(const float4*)(dB - 4*g - 3);
            float4 x4 = *(const float4*)(xB - 4*g - 3);
            S1(d4.w, x4.w, 4*g)   S1(d4.z, x4.z, 4*g+1)
            S1(d4.y, x4.y, 4*g+2) S1(d4.x, x4.x, 4*g+3)
        }
    }
#undef S1
    *(float4*)&lp[ch][n0] = make_float4(exp2f(a2.x*sdl), exp2f(a2.y*sdl),
                                        exp2f(a2.z*sdl), exp2f(a2.w*sdl));
    *(float4*)&ls[ch][n0] = h;
    __syncthreads();

    // ---- scan of 256 summaries: serial-4 -> KS over 64 groups -> apply ----
    const int sn = tid & 15, sg = tid >> 4;        // sg in [0,64)
    float LPe[4], LSe[4];
    {
        float P = 1.f, S = 0.f;
        #pragma unroll
        for (int i = 0; i < 4; ++i) {
            LPe[i] = P; LSe[i] = S;
            float p = lp[sg * 4 + i][sn], s = ls[sg * 4 + i][sn];
            S = fmaf(p, S, s); P = p * P;
        }
        __syncthreads();                           // phase-A reads done
        gpf[tid] = P; gpf[1024 + tid] = S;         // overwrites lp rows 0..127
    }
    __syncthreads();
    #pragma unroll
    for (int off = 1; off < 64; off <<= 1) {
        float pc = gpf[tid], sc = gpf[1024 + tid];
        float pn = pc, snn = sc;
        if (sg >= off) {
            pn  = pc * gpf[tid - off * 16];
            snn = fmaf(pc, gpf[1024 + tid - off * 16], sc);
        }
        __syncthreads();
        gpf[tid] = pn; gpf[1024 + tid] = snn;
        __syncthreads();
    }
    const float GS = (sg == 0) ? 0.f : gpf[1024 + tid - 16];
    #pragma unroll
    for (int i = 0; i < 4; ++i) ls[sg * 4 + i][sn] = fmaf(LPe[i], GS, LSe[i]);
    __syncthreads();

    // ---- pass 2: replay with exclusive init; unified scan-raster store -----
    h = *(float4*)&ls[ch][n0];
    float* yq = y + (long)seq * cL + ch * CL;      // scan-raster, ascending
    float yhold = 0.f;
#define S2(DL, XV, SI, OFF) { \
        float4 B = *(const float4*)(bcB + (OFF) * 8192); \
        float4 C = *(const float4*)(bcB + (OFF) * 8192 + 16); \
        float t = (DL) * (XV); \
        h.x = fmaf(exp2f((DL)*a2.x), h.x, t*B.x); \
        h.y = fmaf(exp2f((DL)*a2.y), h.y, t*B.y); \
        h.z = fmaf(exp2f((DL)*a2.z), h.z, t*B.z); \
        h.w = fmaf(exp2f((DL)*a2.w), h.w, t*B.w); \
        float pv = fmaf(h.x, C.x, fmaf(h.y, C.y, fmaf(h.z, C.z, h.w * C.w))); \
        pv += qperm<0xB1>(pv); \
        pv += qperm<0x4E>(pv); \
        if ((SI) == r) yhold = fmaf(Dv, (XV), pv); }
    if (!rev) {
        #pragma unroll
        for (int g = 0; g < 9; ++g) {
            float4 d4 = *(const float4*)(dB + 4*g);
            float4 x4 = *(const float4*)(xB + 4*g);
            S2(d4.x, x4.x, 0, 4*g)   S2(d4.y, x4.y, 1, 4*g+1)
            S2(d4.z, x4.z, 2, 4*g+2) S2(d4.w, x4.w, 3, 4*g+3)
            yq[4*g + r] = yhold;
        }
    } else {
        #pragma unroll
        for (int g = 0; g < 9; ++g) {
            float4 d4 = *(const float4*)(dB - 4*g - 3);
            float4 x4 = *(const float4*)(xB - 4*g - 3);
            S2(d4.w, x4.w, 0, 4*g)   S2(d4.z, x4.z, 1, 4*g+1)
            S2(d4.y, x4.y, 2, 4*g+2) S2(d4.x, x4.x, 3, 4*g+3)
            yq[4*g + r] = yhold;
        }
    }
#undef S2
}

// ---- kU: transpose Y1,Y3 (scan raster -> spatial raster) -------------------
__global__ __launch_bounds__(256) void kU(const float* __restrict__ Y,
                                          float* __restrict__ YT) {
    __shared__ float t[32][33];
    const int i0 = blockIdx.x * 32, j0 = blockIdx.y * 32;
    const int z = blockIdx.z;
    const int arr = z / 96, d = z % 96;              // arr 0 -> Y1, 1 -> Y3
    const float* src = Y + (1 + 2 * arr) * cDL + (long)d * cL;
    float* dst = YT + (long)arr * cDL + (long)d * cL;
    for (int o = threadIdx.x; o < 1024; o += 256) {
        int i = o >> 5, j = o & 31;
        t[i][j] = src[(i0 + i) * 96 + j0 + j];
    }
    __syncthreads();
    for (int o = threadIdx.x; o < 1024; o += 256) {
        int i = o >> 5, j = o & 31;
        dst[(j0 + i) * 96 + i0 + j] = t[j][i];
    }
}

// ---- kE: 4-dir sum + LayerNorm; Y0/Y1T direct, Y2/Y3T reversed -------------
__global__ __launch_bounds__(256) void kE(const float* __restrict__ Y,
                                          const float* __restrict__ YT,
                                          const float* __restrict__ lnw,
                                          const float* __restrict__ lnb,
                                          float* __restrict__ out) {
    __shared__ float vs[96][36];
    __shared__ float red[8][32], red2[8][32];
    __shared__ float MU[32], RS[32];
    const int tid = threadIdx.x;
    const int p0 = blockIdx.x * 32;

    for (int o = tid; o < 96 * 8; o += 256) {
        int dd = o >> 3, j = o & 7;
        const float* r0 = Y + (long)dd * cL + p0;                  // Y0 direct
        const float* r1 = YT + (long)dd * cL + p0;                 // Y1T direct
        const float* r2 = Y + 2 * cDL + (long)dd * cL;             // Y2 reversed
        const float* r3 = YT + cDL + (long)dd * cL;                // Y3T reversed
        float4 a = ((const float4*)r0)[j];
        float4 b = ((const float4*)r1)[j];
        float4 c = *(const float4*)(r2 + 9212 - p0 - 4 * j);
        float4 e = *(const float4*)(r3 + 9212 - p0 - 4 * j);
        *(float4*)&vs[dd][4 * j] = make_float4(a.x + b.x + c.w + e.w,
                                               a.y + b.y + c.z + e.z,
                                               a.z + b.z + c.y + e.y,
                                               a.w + b.w + c.x + e.x);
    }
    __syncthreads();

    const int p = tid & 31, part = tid >> 5;
    float s = 0.f, s2 = 0.f;
    for (int dd = part * 12; dd < part * 12 + 12; ++dd) {
        float v = vs[dd][p];
        s += v; s2 = fmaf(v, v, s2);
    }
    red[part][p] = s; red2[part][p] = s2;
    __syncthreads();
    if (tid < 32) {
        float S = 0.f, S2 = 0.f;
        #pragma unroll
        for (int q = 0; q < 8; ++q) { S += red[q][tid]; S2 += red2[q][tid]; }
        float m = S * (1.f / 96.f);
        MU[tid] = m;
        RS[tid] = rsqrtf(S2 * (1.f / 96.f) - m * m + 1e-5f);
    }
    __syncthreads();
    for (int o = tid; o < 32 * 96; o += 256) {
        int pl = o / 96, dd = o - pl * 96;
        out[(long)(p0 + pl) * 96 + dd] = (vs[dd][pl] - MU[pl]) * RS[pl] * lnw[dd] + lnb[dd];
    }
}

extern "C" void kernel_launch(void* const* d_in, const int* in_sizes, int n_in,
                              void* d_out, int out_size, void* d_ws, size_t ws_size,
                              hipStream_t stream) {
    const float* x    = (const float*)d_in[0];
    const float* xpw  = (const float*)d_in[1];
    const float* dtw  = (const float*)d_in[2];
    const float* dtb  = (const float*)d_in[3];
    const float* Alog = (const float*)d_in[4];
    const float* Dsv  = (const float*)d_in[5];
    const float* lnw  = (const float*)d_in[6];
    const float* lnb  = (const float*)d_in[7];
    float* ws = (float*)d_ws;

    float* xT    = ws + OFF_XT;
    float* delta = ws + OFF_DELTA;
    float* BC    = ws + OFF_BC;
    float* y     = ws + OFF_Y;
    float* yT    = ws + OFF_YT;
    float* out   = (float*)d_out;

    kT<<<dim3(3, 3, 96), 256, 0, stream>>>(x, xT);
    kA<<<dim3(144, 4), 256, 0, stream>>>(x, xT, xpw, dtw, dtb, delta, BC);
    kS<<<cK * cD, 1024, 0, stream>>>(x, xT, delta, BC, Alog, Dsv, y);
    kU<<<dim3(3, 3, 192), 256, 0, stream>>>(y, yT);
    kE<<<288, 256, 0, stream>>>(y, yT, lnw, lnb, out);
}

// Round 14
// 111.372 us; speedup vs baseline: 1.0204x; 1.0204x over previous
//
#include <hip/hip_runtime.h>
#include <math.h>

// SS2D: B=1, D=96, H=W=96, L=9216, K=4, N=16, R=6
constexpr int cD = 96, cL = 9216, cK = 4;
constexpr int CL = 36, NCH = 256;       // 256 chunks of 36; 128 per half-block
constexpr long cDL = (long)cD * cL;
constexpr float LOG2E = 1.44269504088896f;

// ws float offsets (~48 MB)
constexpr long OFF_XT    = 0;                       // [96][9216]
constexpr long OFF_DELTA = OFF_XT    + cDL;         // [K][96][9216] d-major
constexpr long OFF_BC    = OFF_DELTA + 4L*cDL;      // [K][9][256][4][32] group-major
constexpr long OFF_Y     = OFF_BC    + 4L*cL*32;    // [K][96][9216] scan-raster
constexpr long OFF_YT    = OFF_Y     + 4L*cDL;      // [2][96][9216] Y1T,Y3T
constexpr long OFF_PG    = OFF_YT    + 2L*cDL;      // [384][256][16]
constexpr long OFF_SG    = OFF_PG    + 384L*256*16; // [384][256][16]

__device__ __forceinline__ float4 a2prep(float4 v) {
    return make_float4(-LOG2E * exp2f(LOG2E * v.x), -LOG2E * exp2f(LOG2E * v.y),
                       -LOG2E * exp2f(LOG2E * v.z), -LOG2E * exp2f(LOG2E * v.w));
}
template<int C>
__device__ __forceinline__ float qperm(float v) {
    return __int_as_float(__builtin_amdgcn_mov_dpp(__float_as_int(v), C, 0xf, 0xf, true));
}

// ---- kT: xT[d][w*96+h] = x[d][h*96+w] --------------------------------------
__global__ __launch_bounds__(256) void kT(const float* __restrict__ x,
                                          float* __restrict__ xT) {
    __shared__ float t[32][33];
    const int h0 = blockIdx.x * 32, w0 = blockIdx.y * 32, d = blockIdx.z;
    const float* xd = x + (long)d * cL;
    float* xtd = xT + (long)d * cL;
    for (int o = threadIdx.x; o < 1024; o += 256) {
        int i = o >> 5, j = o & 31;
        t[i][j] = xd[(h0 + i) * 96 + w0 + j];
    }
    __syncthreads();
    for (int o = threadIdx.x; o < 1024; o += 256) {
        int i = o >> 5, j = o & 31;
        xtd[(w0 + i) * 96 + h0 + j] = t[j][i];
    }
}

// ---- kA: G = W_k @ src_k; delta[k][d][p], BC[k][9][256][4][32] -------------
__global__ __launch_bounds__(256) void kA(const float* __restrict__ x,
                                          const float* __restrict__ xT,
                                          const float* __restrict__ xpw,
                                          const float* __restrict__ dtw,
                                          const float* __restrict__ dtb,
                                          float* __restrict__ delta,
                                          float* __restrict__ BC) {
    __shared__ float xs[96][64];
    __shared__ float xdbl[38][65];
    __shared__ float dtw_l[96 * 6];
    __shared__ float dtb_l[96];
    const int p0 = blockIdx.x * 64;
    const int k  = blockIdx.y;
    const int tid = threadIdx.x;
    const float* src = (k & 1) ? xT : x;

    for (int o = tid; o < 96 * 64; o += 256) {
        int dd = o >> 6, pp = o & 63;
        xs[dd][pp] = src[(long)dd * cL + p0 + pp];
    }
    for (int o = tid; o < 96 * 6; o += 256) dtw_l[o] = dtw[k * 96 * 6 + o];
    if (tid < 96) dtb_l[tid] = dtb[k * 96 + tid];
    __syncthreads();

    const int lane = tid & 63;
    const int c0 = __builtin_amdgcn_readfirstlane((tid >> 6) * 10);
    const float* wk = xpw + (long)k * 38 * 96;
    float acc[10];
    #pragma unroll
    for (int i = 0; i < 10; ++i) acc[i] = 0.f;
    #pragma unroll 4
    for (int dd = 0; dd < 96; ++dd) {
        float xv = xs[dd][lane];
        #pragma unroll
        for (int i = 0; i < 10; ++i) {
            int c = c0 + i; c = c > 37 ? 37 : c;
            acc[i] = fmaf(xv, wk[c * 96 + dd], acc[i]);
        }
    }
    #pragma unroll
    for (int i = 0; i < 10; ++i) {
        int c = c0 + i; c = c > 37 ? 37 : c;
        xdbl[c][lane] = acc[i];
    }
    __syncthreads();

    // BC group-major: q = scan idx; ch=q/36, j=q%36, g=j>>2, r=j&3
    for (int o = tid; o < 64 * 16; o += 256) {
        int n = o & 15, pp = o >> 4;
        int P = p0 + pp;
        int q = (k < 2) ? P : (9215 - P);
        int ch = q / 36, j = q - ch * 36;
        int g = j >> 2, r = j & 3;
        long idx = ((((long)k * 9 + g) * 256 + ch) * 4 + r) * 32 + n;
        BC[idx]      = xdbl[6 + n][pp];
        BC[idx + 16] = xdbl[22 + n][pp];
    }
    for (int o = tid; o < 96 * 64; o += 256) {
        int dd = o >> 6, pp = o & 63;
        float s = dtb_l[dd];
        #pragma unroll
        for (int r = 0; r < 6; ++r) s = fmaf(xdbl[r][pp], dtw_l[dd * 6 + r], s);
        float sp = fmaxf(s, 0.f) + __logf(1.f + __expf(-fabsf(s)));
        delta[((long)(k * 96 + dd)) * cL + p0 + pp] = sp;
    }
}

// ---- kS1: half-seq chunk summaries -> Pg/Sg. 768 blocks x 512 thr ----------
__global__ __launch_bounds__(512, 6) void kS1(const float* __restrict__ x,
                                              const float* __restrict__ xT,
                                              const float* __restrict__ delta,
                                              const float* __restrict__ BC,
                                              const float* __restrict__ Alog,
                                              float* __restrict__ Pg,
                                              float* __restrict__ Sg) {
    const int tid = threadIdx.x;
    const int n0 = (tid & 3) * 4, chl = tid >> 2;   // chl in [0,128)
    const int hb = blockIdx.x & 1, seq = blockIdx.x >> 1;
    const int k = seq / 96, d = seq % 96, rev = k >> 1;
    const int ch = hb * 128 + chl;
    const int q0 = ch * CL;                          // scan index of chunk start

    const float4 a2 = a2prep(*(const float4*)(Alog + (long)seq * 16 + n0));
    // spatial base for scan idx q: fwd p=q, rev p=9215-q
    const float* dRow = delta + (long)seq * cL;
    const float* xRow = ((k & 1) ? xT : x) + (long)d * cL;
    const float* bc0 = BC + ((long)k * 9 * 256 * 4 + (long)ch * 4) * 32 + n0;

    float4 h = make_float4(0.f, 0.f, 0.f, 0.f);
    float sdl = 0.f;
#define ST(DL, XV, BPTR, ROFF) { \
        float4 B = *(const float4*)((BPTR) + (ROFF) * 32); \
        float t = (DL) * (XV); sdl += (DL); \
        h.x = fmaf(exp2f((DL)*a2.x), h.x, t*B.x); \
        h.y = fmaf(exp2f((DL)*a2.y), h.y, t*B.y); \
        h.z = fmaf(exp2f((DL)*a2.z), h.z, t*B.z); \
        h.w = fmaf(exp2f((DL)*a2.w), h.w, t*B.w); }
    #pragma unroll
    for (int g = 0; g < 9; ++g) {
        const float* bg = bc0 + (long)g * 32768;     // [k][g][ch][0][n0]
        if (!rev) {
            float4 d4 = *(const float4*)(dRow + q0 + 4 * g);
            float4 x4 = *(const float4*)(xRow + q0 + 4 * g);
            ST(d4.x, x4.x, bg, 0) ST(d4.y, x4.y, bg, 1)
            ST(d4.z, x4.z, bg, 2) ST(d4.w, x4.w, bg, 3)
        } else {
            float4 d4 = *(const float4*)(dRow + 9212 - q0 - 4 * g);
            float4 x4 = *(const float4*)(xRow + 9212 - q0 - 4 * g);
            ST(d4.w, x4.w, bg, 0) ST(d4.z, x4.z, bg, 1)
            ST(d4.y, x4.y, bg, 2) ST(d4.x, x4.x, bg, 3)
        }
    }
#undef ST
    long o = ((long)seq * NCH + ch) * 16 + n0;
    *(float4*)(Pg + o) = make_float4(exp2f(a2.x*sdl), exp2f(a2.y*sdl),
                                     exp2f(a2.z*sdl), exp2f(a2.w*sdl));
    *(float4*)(Sg + o) = h;
}

// ---- kS2: LDS scan of 256 summaries + replay half + scan-raster y ----------
__global__ __launch_bounds__(512, 6) void kS2(const float* __restrict__ x,
                                              const float* __restrict__ xT,
                                              const float* __restrict__ delta,
                                              const float* __restrict__ BC,
                                              const float* __restrict__ Alog,
                                              const float* __restrict__ Dsv,
                                              const float* __restrict__ Pg,
                                              const float* __restrict__ Sg,
                                              float* __restrict__ y) {
    __shared__ float lp[NCH][16];        // 16 KB
    __shared__ float ls[NCH][16];        // 16 KB
    float* gpf = &lp[0][0];              // aliased after phase A
    const int tid = threadIdx.x;
    const int hb = blockIdx.x & 1, seq = blockIdx.x >> 1;
    const int k = seq / 96, d = seq % 96, rev = k >> 1;

    #pragma unroll
    for (int i = 0; i < 8; ++i) {
        ((float*)lp)[tid + i * 512] = Pg[(long)seq * 4096 + tid + i * 512];
        ((float*)ls)[tid + i * 512] = Sg[(long)seq * 4096 + tid + i * 512];
    }
    __syncthreads();

    // phase A: serial scan of 8 chunks per thread
    const int sn = tid & 15, sg = tid >> 4;          // sg in [0,32)
    float LPe[8], LSe[8];
    {
        float P = 1.f, S = 0.f;
        #pragma unroll
        for (int i = 0; i < 8; ++i) {
            LPe[i] = P; LSe[i] = S;
            float p = lp[sg * 8 + i][sn], s = ls[sg * 8 + i][sn];
            S = fmaf(p, S, s); P = p * P;
        }
        __syncthreads();
        gpf[tid] = P; gpf[512 + tid] = S;
    }
    __syncthreads();
    // phase B: Kogge-Stone over 32 groups
    #pragma unroll
    for (int off = 1; off < 32; off <<= 1) {
        float pc = gpf[tid], sc = gpf[512 + tid];
        float pn = pc, snn = sc;
        if (sg >= off) {
            pn  = pc * gpf[tid - off * 16];
            snn = fmaf(pc, gpf[512 + tid - off * 16], sc);
        }
        __syncthreads();
        gpf[tid] = pn; gpf[512 + tid] = snn;
        __syncthreads();
    }
    const float GS = (sg == 0) ? 0.f : gpf[512 + tid - 16];
    // phase C: exclusive per-chunk init -> ls
    #pragma unroll
    for (int i = 0; i < 8; ++i) ls[sg * 8 + i][sn] = fmaf(LPe[i], GS, LSe[i]);
    __syncthreads();

    // replay this block's half
    const int n0 = (tid & 3) * 4, chl = tid >> 2;
    const int r = tid & 3;
    const int ch = hb * 128 + chl;
    const int q0 = ch * CL;
    const float4 a2 = a2prep(*(const float4*)(Alog + (long)seq * 16 + n0));
    const float Dv = Dsv[seq];
    const float* dRow = delta + (long)seq * cL;
    const float* xRow = ((k & 1) ? xT : x) + (long)d * cL;
    const float* bc0 = BC + ((long)k * 9 * 256 * 4 + (long)ch * 4) * 32 + n0;
    float4 h = *(float4*)&ls[ch][n0];
    float* yq = y + (long)seq * cL + q0;             // scan-raster, ascending
    float yhold = 0.f;

#define ST(DL, XV, BPTR, ROFF, SI) { \
        float4 B = *(const float4*)((BPTR) + (ROFF) * 32); \
        float4 C = *(const float4*)((BPTR) + (ROFF) * 32 + 16); \
        float t = (DL) * (XV); \
        h.x = fmaf(exp2f((DL)*a2.x), h.x, t*B.x); \
        h.y = fmaf(exp2f((DL)*a2.y), h.y, t*B.y); \
        h.z = fmaf(exp2f((DL)*a2.z), h.z, t*B.z); \
        h.w = fmaf(exp2f((DL)*a2.w), h.w, t*B.w); \
        float pv = fmaf(h.x, C.x, fmaf(h.y, C.y, fmaf(h.z, C.z, h.w * C.w))); \
        pv += qperm<0xB1>(pv); \
        pv += qperm<0x4E>(pv); \
        if ((SI) == r) yhold = fmaf(Dv, (XV), pv); }
    #pragma unroll
    for (int g = 0; g < 9; ++g) {
        const float* bg = bc0 + (long)g * 32768;
        if (!rev) {
            float4 d4 = *(const float4*)(dRow + q0 + 4 * g);
            float4 x4 = *(const float4*)(xRow + q0 + 4 * g);
            ST(d4.x, x4.x, bg, 0, 0) ST(d4.y, x4.y, bg, 1, 1)
            ST(d4.z, x4.z, bg, 2, 2) ST(d4.w, x4.w, bg, 3, 3)
        } else {
            float4 d4 = *(const float4*)(dRow + 9212 - q0 - 4 * g);
            float4 x4 = *(const float4*)(xRow + 9212 - q0 - 4 * g);
            ST(d4.w, x4.w, bg, 0, 0) ST(d4.z, x4.z, bg, 1, 1)
            ST(d4.y, x4.y, bg, 2, 2) ST(d4.x, x4.x, bg, 3, 3)
        }
        yq[4 * g + r] = yhold;
    }
#undef ST
}

// ---- kU: transpose Y1,Y3 (scan raster -> spatial raster) -------------------
__global__ __launch_bounds__(256) void kU(const float* __restrict__ Y,
                                          float* __restrict__ YT) {
    __shared__ float t[32][33];
    const int i0 = blockIdx.x * 32, j0 = blockIdx.y * 32;
    const int z = blockIdx.z;
    const int arr = z / 96, d = z % 96;              // arr 0 -> Y1, 1 -> Y3
    const float* src = Y + (1 + 2 * arr) * cDL + (long)d * cL;
    float* dst = YT + (long)arr * cDL + (long)d * cL;
    for (int o = threadIdx.x; o < 1024; o += 256) {
        int i = o >> 5, j = o & 31;
        t[i][j] = src[(i0 + i) * 96 + j0 + j];
    }
    __syncthreads();
    for (int o = threadIdx.x; o < 1024; o += 256) {
        int i = o >> 5, j = o & 31;
        dst[(j0 + i) * 96 + i0 + j] = t[j][i];
    }
}

// ---- kE: 4-dir sum + LayerNorm; Y0/Y1T direct, Y2/Y3T reversed -------------
__global__ __launch_bounds__(256) void kE(const float* __restrict__ Y,
                                          const float* __restrict__ YT,
                                          const float* __restrict__ lnw,
                                          const float* __restrict__ lnb,
                                          float* __restrict__ out) {
    __shared__ float vs[96][36];
    __shared__ float red[8][32], red2[8][32];
    __shared__ float MU[32], RS[32];
    const int tid = threadIdx.x;
    const int p0 = blockIdx.x * 32;

    for (int o = tid; o < 96 * 8; o += 256) {
        int dd = o >> 3, j = o & 7;
        const float* r0 = Y + (long)dd * cL + p0;
        const float* r1 = YT + (long)dd * cL + p0;
        const float* r2 = Y + 2 * cDL + (long)dd * cL;
        const float* r3 = YT + cDL + (long)dd * cL;
        float4 a = ((const float4*)r0)[j];
        float4 b = ((const float4*)r1)[j];
        float4 c = *(const float4*)(r2 + 9212 - p0 - 4 * j);
        float4 e = *(const float4*)(r3 + 9212 - p0 - 4 * j);
        *(float4*)&vs[dd][4 * j] = make_float4(a.x + b.x + c.w + e.w,
                                               a.y + b.y + c.z + e.z,
                                               a.z + b.z + c.y + e.y,
                                               a.w + b.w + c.x + e.x);
    }
    __syncthreads();

    const int p = tid & 31, part = tid >> 5;
    float s = 0.f, s2 = 0.f;
    for (int dd = part * 12; dd < part * 12 + 12; ++dd) {
        float v = vs[dd][p];
        s += v; s2 = fmaf(v, v, s2);
    }
    red[part][p] = s; red2[part][p] = s2;
    __syncthreads();
    if (tid < 32) {
        float S = 0.f, S2 = 0.f;
        #pragma unroll
        for (int q = 0; q < 8; ++q) { S += red[q][tid]; S2 += red2[q][tid]; }
        float m = S * (1.f / 96.f);
        MU[tid] = m;
        RS[tid] = rsqrtf(S2 * (1.f / 96.f) - m * m + 1e-5f);
    }
    __syncthreads();
    for (int o = tid; o < 32 * 96; o += 256) {
        int pl = o / 96, dd = o - pl * 96;
        out[(long)(p0 + pl) * 96 + dd] = (vs[dd][pl] - MU[pl]) * RS[pl] * lnw[dd] + lnb[dd];
    }
}

extern "C" void kernel_launch(void* const* d_in, const int* in_sizes, int n_in,
                              void* d_out, int out_size, void* d_ws, size_t ws_size,
                              hipStream_t stream) {
    const float* x    = (const float*)d_in[0];
    const float* xpw  = (const float*)d_in[1];
    const float* dtw  = (const float*)d_in[2];
    const float* dtb  = (const float*)d_in[3];
    const float* Alog = (const float*)d_in[4];
    const float* Dsv  = (const float*)d_in[5];
    const float* lnw  = (const float*)d_in[6];
    const float* lnb  = (const float*)d_in[7];
    float* ws = (float*)d_ws;

    float* xT    = ws + OFF_XT;
    float* delta = ws + OFF_DELTA;
    float* BC    = ws + OFF_BC;
    float* y     = ws + OFF_Y;
    float* yT    = ws + OFF_YT;
    float* Pg    = ws + OFF_PG;
    float* Sg    = ws + OFF_SG;
    float* out   = (float*)d_out;

    kT<<<dim3(3, 3, 96), 256, 0, stream>>>(x, xT);
    kA<<<dim3(144, 4), 256, 0, stream>>>(x, xT, xpw, dtw, dtb, delta, BC);
    kS1<<<768, 512, 0, stream>>>(x, xT, delta, BC, Alog, Pg, Sg);
    kS2<<<768, 512, 0, stream>>>(x, xT, delta, BC, Alog, Dsv, Pg, Sg, y);
    kU<<<dim3(3, 3, 192), 256, 0, stream>>>(y, yT);
    kE<<<288, 256, 0, stream>>>(y, yT, lnw, lnb, out);
}

// Round 15
// 97.429 us; speedup vs baseline: 1.1664x; 1.1431x over previous
//
#include <hip/hip_runtime.h>
#include <math.h>

// SS2D: B=1, D=96, H=W=96, L=9216, K=4, N=16, R=6
constexpr int cD = 96, cL = 9216, cK = 4;
constexpr int CL = 36, NCH = 256;       // 256 chunks of 36; 128 per half-block
constexpr long cDL = (long)cD * cL;
constexpr float LOG2E = 1.44269504088896f;

// ws float offsets
constexpr long OFF_XT    = 0;                       // [96][9216]
constexpr long OFF_DELTA = OFF_XT    + cDL;         // [K][96][9216] d-major
constexpr long OFF_BC    = OFF_DELTA + 4L*cDL;      // [K][36][256][32] j-major, B|C
constexpr long OFF_Y     = OFF_BC    + 4L*cL*32;    // [K][96][9216] spatial raster
constexpr long OFF_PG    = OFF_Y     + 4L*cDL;      // [384][256][16]
constexpr long OFF_SG    = OFF_PG    + 384L*256*16; // [384][256][16]

__device__ __forceinline__ float4 a2prep(float4 v) {
    return make_float4(-LOG2E * exp2f(LOG2E * v.x), -LOG2E * exp2f(LOG2E * v.y),
                       -LOG2E * exp2f(LOG2E * v.z), -LOG2E * exp2f(LOG2E * v.w));
}
template<int C>
__device__ __forceinline__ float qperm(float v) {
    return __int_as_float(__builtin_amdgcn_mov_dpp(__float_as_int(v), C, 0xf, 0xf, true));
}

// ---- kT: xT[d][w*96+h] = x[d][h*96+w] --------------------------------------
__global__ __launch_bounds__(256) void kT(const float* __restrict__ x,
                                          float* __restrict__ xT) {
    __shared__ float t[32][33];
    const int h0 = blockIdx.x * 32, w0 = blockIdx.y * 32, d = blockIdx.z;
    const float* xd = x + (long)d * cL;
    float* xtd = xT + (long)d * cL;
    for (int o = threadIdx.x; o < 1024; o += 256) {
        int i = o >> 5, j = o & 31;
        t[i][j] = xd[(h0 + i) * 96 + w0 + j];
    }
    __syncthreads();
    for (int o = threadIdx.x; o < 1024; o += 256) {
        int i = o >> 5, j = o & 31;
        xtd[(w0 + i) * 96 + h0 + j] = t[j][i];
    }
}

// ---- kA: G = W_k @ src_k; delta[k][d][p], BC[k][36][256][32] ---------------
__global__ __launch_bounds__(256) void kA(const float* __restrict__ x,
                                          const float* __restrict__ xT,
                                          const float* __restrict__ xpw,
                                          const float* __restrict__ dtw,
                                          const float* __restrict__ dtb,
                                          float* __restrict__ delta,
                                          float* __restrict__ BC) {
    __shared__ float xs[96][64];
    __shared__ float xdbl[38][65];
    __shared__ float dtw_l[96 * 6];
    __shared__ float dtb_l[96];
    const int p0 = blockIdx.x * 64;
    const int k  = blockIdx.y;
    const int tid = threadIdx.x;
    const float* src = (k & 1) ? xT : x;

    for (int o = tid; o < 96 * 64; o += 256) {
        int dd = o >> 6, pp = o & 63;
        xs[dd][pp] = src[(long)dd * cL + p0 + pp];
    }
    for (int o = tid; o < 96 * 6; o += 256) dtw_l[o] = dtw[k * 96 * 6 + o];
    if (tid < 96) dtb_l[tid] = dtb[k * 96 + tid];
    __syncthreads();

    const int lane = tid & 63;
    const int c0 = __builtin_amdgcn_readfirstlane((tid >> 6) * 10);
    const float* wk = xpw + (long)k * 38 * 96;
    float acc[10];
    #pragma unroll
    for (int i = 0; i < 10; ++i) acc[i] = 0.f;
    #pragma unroll 4
    for (int dd = 0; dd < 96; ++dd) {
        float xv = xs[dd][lane];
        #pragma unroll
        for (int i = 0; i < 10; ++i) {
            int c = c0 + i; c = c > 37 ? 37 : c;
            acc[i] = fmaf(xv, wk[c * 96 + dd], acc[i]);
        }
    }
    #pragma unroll
    for (int i = 0; i < 10; ++i) {
        int c = c0 + i; c = c > 37 ? 37 : c;
        xdbl[c][lane] = acc[i];
    }
    __syncthreads();

    // BC j-major: q = scan idx; ch = q/36, j = q%36; B at +0, C at +16
    for (int o = tid; o < 64 * 16; o += 256) {
        int n = o & 15, pp = o >> 4;
        int P = p0 + pp;
        int q = (k < 2) ? P : (9215 - P);
        int ch = q / 36, j = q - ch * 36;
        long idx = (((long)k * 36 + j) * 256 + ch) * 32 + n;
        BC[idx]      = xdbl[6 + n][pp];
        BC[idx + 16] = xdbl[22 + n][pp];
    }
    for (int o = tid; o < 96 * 64; o += 256) {
        int dd = o >> 6, pp = o & 63;
        float s = dtb_l[dd];
        #pragma unroll
        for (int r = 0; r < 6; ++r) s = fmaf(xdbl[r][pp], dtw_l[dd * 6 + r], s);
        float sp = fmaxf(s, 0.f) + __logf(1.f + __expf(-fabsf(s)));
        delta[((long)(k * 96 + dd)) * cL + p0 + pp] = sp;
    }
}

// ---- kS1: half-seq chunk summaries -> Pg/Sg. 768 blocks x 512 thr ----------
__global__ __launch_bounds__(512, 5) void kS1(const float* __restrict__ x,
                                              const float* __restrict__ xT,
                                              const float* __restrict__ delta,
                                              const float* __restrict__ BC,
                                              const float* __restrict__ Alog,
                                              float* __restrict__ Pg,
                                              float* __restrict__ Sg) {
    const int tid = threadIdx.x;
    const int n0 = (tid & 3) * 4, chl = tid >> 2;   // chl in [0,128)
    const int hb = blockIdx.x & 1, seq = blockIdx.x >> 1;
    const int k = seq / 96, d = seq % 96, rev = k >> 1;
    const int ch = hb * 128 + chl;
    const int q0 = ch * CL;

    const float4 a2 = a2prep(*(const float4*)(Alog + (long)seq * 16 + n0));
    const float* dRow = delta + (long)seq * cL;     // indexed by spatial p
    const float* xRow = ((k & 1) ? xT : x) + (long)d * cL;
    const float* bc = BC + ((long)k * 36 * 256 + ch) * 32 + n0;

    float4 h = make_float4(0.f, 0.f, 0.f, 0.f);
    float sdl = 0.f;
#define STEP1(DL, XV, B) { \
        float t = (DL) * (XV); sdl += (DL); \
        h.x = fmaf(exp2f((DL)*a2.x), h.x, t*(B).x); \
        h.y = fmaf(exp2f((DL)*a2.y), h.y, t*(B).y); \
        h.z = fmaf(exp2f((DL)*a2.z), h.z, t*(B).z); \
        h.w = fmaf(exp2f((DL)*a2.w), h.w, t*(B).w); }
    #pragma unroll
    for (int g = 0; g < 9; ++g) {
        const float* bj = bc + (long)(4 * g) * 8192;
        float4 B0 = *(const float4*)(bj);
        float4 B1 = *(const float4*)(bj + 8192);
        float4 B2 = *(const float4*)(bj + 16384);
        float4 B3 = *(const float4*)(bj + 24576);
        float4 d4, x4;
        if (!rev) {
            d4 = *(const float4*)(dRow + q0 + 4 * g);
            x4 = *(const float4*)(xRow + q0 + 4 * g);
            STEP1(d4.x, x4.x, B0) STEP1(d4.y, x4.y, B1)
            STEP1(d4.z, x4.z, B2) STEP1(d4.w, x4.w, B3)
        } else {
            d4 = *(const float4*)(dRow + 9212 - q0 - 4 * g);
            x4 = *(const float4*)(xRow + 9212 - q0 - 4 * g);
            STEP1(d4.w, x4.w, B0) STEP1(d4.z, x4.z, B1)
            STEP1(d4.y, x4.y, B2) STEP1(d4.x, x4.x, B3)
        }
    }
#undef STEP1
    long o = ((long)seq * NCH + ch) * 16 + n0;
    *(float4*)(Pg + o) = make_float4(exp2f(a2.x*sdl), exp2f(a2.y*sdl),
                                     exp2f(a2.z*sdl), exp2f(a2.w*sdl));
    *(float4*)(Sg + o) = h;
}

// ---- kS2: LDS scan of 256 summaries + replay half + ybuf writeout ----------
__global__ __launch_bounds__(512, 3) void kS2(const float* __restrict__ x,
                                              const float* __restrict__ xT,
                                              const float* __restrict__ delta,
                                              const float* __restrict__ BC,
                                              const float* __restrict__ Alog,
                                              const float* __restrict__ Dsv,
                                              const float* __restrict__ Pg,
                                              const float* __restrict__ Sg,
                                              float* __restrict__ y) {
    __shared__ float lp[NCH][16];        // 16 KB
    __shared__ float ls[NCH][16];        // 16 KB
    __shared__ float ybuf[4608 + 48];    // 18.6 KB
    float* gpf = &lp[0][0];              // aliased after phase A
    const int tid = threadIdx.x;
    const int hb = blockIdx.x & 1, seq = blockIdx.x >> 1;
    const int k = seq / 96, d = seq % 96, rev = k >> 1;

    #pragma unroll
    for (int i = 0; i < 8; ++i) {
        ((float*)lp)[tid + i * 512] = Pg[(long)seq * 4096 + tid + i * 512];
        ((float*)ls)[tid + i * 512] = Sg[(long)seq * 4096 + tid + i * 512];
    }
    __syncthreads();

    // phase A: serial scan of 8 chunks per thread
    const int sn = tid & 15, sg = tid >> 4;          // sg in [0,32)
    float LPe[8], LSe[8];
    {
        float P = 1.f, S = 0.f;
        #pragma unroll
        for (int i = 0; i < 8; ++i) {
            LPe[i] = P; LSe[i] = S;
            float p = lp[sg * 8 + i][sn], s = ls[sg * 8 + i][sn];
            S = fmaf(p, S, s); P = p * P;
        }
        __syncthreads();
        gpf[tid] = P; gpf[512 + tid] = S;
    }
    __syncthreads();
    // phase B: Kogge-Stone over 32 groups
    #pragma unroll
    for (int off = 1; off < 32; off <<= 1) {
        float pc = gpf[tid], sc = gpf[512 + tid];
        float pn = pc, snn = sc;
        if (sg >= off) {
            pn  = pc * gpf[tid - off * 16];
            snn = fmaf(pc, gpf[512 + tid - off * 16], sc);
        }
        __syncthreads();
        gpf[tid] = pn; gpf[512 + tid] = snn;
        __syncthreads();
    }
    const float GS = (sg == 0) ? 0.f : gpf[512 + tid - 16];
    // phase C: exclusive per-chunk init -> ls
    #pragma unroll
    for (int i = 0; i < 8; ++i) ls[sg * 8 + i][sn] = fmaf(LPe[i], GS, LSe[i]);
    __syncthreads();

    // replay this block's half
    const int n0 = (tid & 3) * 4, chl = tid >> 2;
    const int r = tid & 3;
    const int ch = hb * 128 + chl;
    const int q0 = ch * CL;
    const int slB = chl * CL;
    const float4 a2 = a2prep(*(const float4*)(Alog + (long)seq * 16 + n0));
    const float Dv = Dsv[seq];
    const float* dRow = delta + (long)seq * cL;
    const float* xRow = ((k & 1) ? xT : x) + (long)d * cL;
    const float* bc = BC + ((long)k * 36 * 256 + ch) * 32 + n0;
    float4 h = *(float4*)&ls[ch][n0];
    float yhold = 0.f;

#define STEP2(DL, XV, B, C, SI) { \
        float t = (DL) * (XV); \
        h.x = fmaf(exp2f((DL)*a2.x), h.x, t*(B).x); \
        h.y = fmaf(exp2f((DL)*a2.y), h.y, t*(B).y); \
        h.z = fmaf(exp2f((DL)*a2.z), h.z, t*(B).z); \
        h.w = fmaf(exp2f((DL)*a2.w), h.w, t*(B).w); \
        float pv = fmaf(h.x, (C).x, fmaf(h.y, (C).y, fmaf(h.z, (C).z, h.w * (C).w))); \
        pv += qperm<0xB1>(pv); \
        pv += qperm<0x4E>(pv); \
        if ((SI) == r) yhold = fmaf(Dv, (XV), pv); }
    #pragma unroll
    for (int g = 0; g < 9; ++g) {
        const float* bj = bc + (long)(4 * g) * 8192;
        float4 B0 = *(const float4*)(bj);
        float4 C0 = *(const float4*)(bj + 16);
        float4 B1 = *(const float4*)(bj + 8192);
        float4 C1 = *(const float4*)(bj + 8192 + 16);
        float4 B2 = *(const float4*)(bj + 16384);
        float4 C2 = *(const float4*)(bj + 16384 + 16);
        float4 B3 = *(const float4*)(bj + 24576);
        float4 C3 = *(const float4*)(bj + 24576 + 16);
        float4 d4, x4;
        if (!rev) {
            d4 = *(const float4*)(dRow + q0 + 4 * g);
            x4 = *(const float4*)(xRow + q0 + 4 * g);
            STEP2(d4.x, x4.x, B0, C0, 0) STEP2(d4.y, x4.y, B1, C1, 1)
            STEP2(d4.z, x4.z, B2, C2, 2) STEP2(d4.w, x4.w, B3, C3, 3)
        } else {
            d4 = *(const float4*)(dRow + 9212 - q0 - 4 * g);
            x4 = *(const float4*)(xRow + 9212 - q0 - 4 * g);
            STEP2(d4.w, x4.w, B0, C0, 0) STEP2(d4.z, x4.z, B1, C1, 1)
            STEP2(d4.y, x4.y, B2, C2, 2) STEP2(d4.x, x4.x, B3, C3, 3)
        }
        int sl = slB + 4 * g + r;
        int yloc = rev ? 4607 - sl : sl;
        ybuf[yloc + yloc / 96] = yhold;
    }
#undef STEP2
    __syncthreads();

    // writeout: ybuf (local spatial order + pad) -> y[seq] spatial raster
    const int sb = rev ? (1 - hb) * 4608 : hb * 4608;
    float* yrow = y + (long)seq * cL;
    if (k & 1) {
        const int w0 = sb / 96;
        for (int o = tid; o < 4608; o += 512) {
            int hh = o / 48, wl = o - hh * 48;
            yrow[hh * 96 + w0 + wl] = ybuf[wl * 97 + hh];
        }
    } else {
        for (int o = tid; o < 4608; o += 512) {
            yrow[sb + o] = ybuf[o + o / 96];
        }
    }
}

// ---- kE: 4-dir sum (all spatial, d-major) + LayerNorm; 32 p per block ------
__global__ __launch_bounds__(256) void kE(const float* __restrict__ y,
                                          const float* __restrict__ lnw,
                                          const float* __restrict__ lnb,
                                          float* __restrict__ out) {
    __shared__ float vs[96][36];
    __shared__ float red[8][32], red2[8][32];
    __shared__ float MU[32], RS[32];
    const int tid = threadIdx.x;
    const int p0 = blockIdx.x * 32;

    for (int o = tid; o < 96 * 8; o += 256) {
        int dd = o >> 3, j = o & 7;
        const float* r0 = y + (long)dd * cL + p0;
        const float* r1 = y + cDL + (long)dd * cL + p0;
        const float* r2 = y + 2 * cDL + (long)dd * cL + p0;
        const float* r3 = y + 3 * cDL + (long)dd * cL + p0;
        float4 a = ((const float4*)r0)[j];
        float4 b = ((const float4*)r1)[j];
        float4 c = ((const float4*)r2)[j];
        float4 e = ((const float4*)r3)[j];
        *(float4*)&vs[dd][4 * j] = make_float4(a.x + b.x + c.x + e.x,
                                               a.y + b.y + c.y + e.y,
                                               a.z + b.z + c.z + e.z,
                                               a.w + b.w + c.w + e.w);
    }
    __syncthreads();

    const int p = tid & 31, part = tid >> 5;
    float s = 0.f, s2 = 0.f;
    for (int dd = part * 12; dd < part * 12 + 12; ++dd) {
        float v = vs[dd][p];
        s += v; s2 = fmaf(v, v, s2);
    }
    red[part][p] = s; red2[part][p] = s2;
    __syncthreads();
    if (tid < 32) {
        float S = 0.f, S2 = 0.f;
        #pragma unroll
        for (int q = 0; q < 8; ++q) { S += red[q][tid]; S2 += red2[q][tid]; }
        float m = S * (1.f / 96.f);
        MU[tid] = m;
        RS[tid] = rsqrtf(S2 * (1.f / 96.f) - m * m + 1e-5f);
    }
    __syncthreads();
    for (int o = tid; o < 32 * 96; o += 256) {
        int pl = o / 96, dd = o - pl * 96;
        out[(long)(p0 + pl) * 96 + dd] = (vs[dd][pl] - MU[pl]) * RS[pl] * lnw[dd] + lnb[dd];
    }
}

extern "C" void kernel_launch(void* const* d_in, const int* in_sizes, int n_in,
                              void* d_out, int out_size, void* d_ws, size_t ws_size,
                              hipStream_t stream) {
    const float* x    = (const float*)d_in[0];
    const float* xpw  = (const float*)d_in[1];
    const float* dtw  = (const float*)d_in[2];
    const float* dtb  = (const float*)d_in[3];
    const float* Alog = (const float*)d_in[4];
    const float* Dsv  = (const float*)d_in[5];
    const float* lnw  = (const float*)d_in[6];
    const float* lnb  = (const float*)d_in[7];
    float* ws = (float*)d_ws;

    float* xT    = ws + OFF_XT;
    float* delta = ws + OFF_DELTA;
    float* BC    = ws + OFF_BC;
    float* y     = ws + OFF_Y;
    float* Pg    = ws + OFF_PG;
    float* Sg    = ws + OFF_SG;
    float* out   = (float*)d_out;

    kT<<<dim3(3, 3, 96), 256, 0, stream>>>(x, xT);
    kA<<<dim3(144, 4), 256, 0, stream>>>(x, xT, xpw, dtw, dtb, delta, BC);
    kS1<<<768, 512, 0, stream>>>(x, xT, delta, BC, Alog, Pg, Sg);
    kS2<<<768, 512, 0, stream>>>(x, xT, delta, BC, Alog, Dsv, Pg, Sg, y);
    kE<<<288, 256, 0, stream>>>(y, lnw, lnb, out);
}

// Round 16
// 92.185 us; speedup vs baseline: 1.2328x; 1.0569x over previous
//
#include <hip/hip_runtime.h>
#include <math.h>

// SS2D: B=1, D=96, H=W=96, L=9216, K=4, N=16, R=6
constexpr int cD = 96, cL = 9216, cK = 4;
constexpr int CL = 36, NCH = 256;       // 256 chunks of 36
constexpr long cDL = (long)cD * cL;
constexpr float LOG2E = 1.44269504088896f;

// ws float offsets
constexpr long OFF_XT    = 0;                       // [96][9216]
constexpr long OFF_DELTA = OFF_XT    + cDL;         // [K][96][9216] d-major
constexpr long OFF_BC    = OFF_DELTA + 4L*cDL;      // [K][36][256][32] j-major, B|C
constexpr long OFF_Y     = OFF_BC    + 4L*cL*32;    // [K][96][9216] spatial raster
constexpr long OFF_PG    = OFF_Y     + 4L*cDL;      // [384][256][16] -> hin
constexpr long OFF_SG    = OFF_PG    + 384L*256*16; // [384][256][16]

__device__ __forceinline__ float4 a2prep(float4 v) {
    return make_float4(-LOG2E * exp2f(LOG2E * v.x), -LOG2E * exp2f(LOG2E * v.y),
                       -LOG2E * exp2f(LOG2E * v.z), -LOG2E * exp2f(LOG2E * v.w));
}
template<int C>
__device__ __forceinline__ float qperm(float v) {
    return __int_as_float(__builtin_amdgcn_mov_dpp(__float_as_int(v), C, 0xf, 0xf, true));
}

// ---- kT: xT[d][w*96+h] = x[d][h*96+w] --------------------------------------
__global__ __launch_bounds__(256) void kT(const float* __restrict__ x,
                                          float* __restrict__ xT) {
    __shared__ float t[32][33];
    const int h0 = blockIdx.x * 32, w0 = blockIdx.y * 32, d = blockIdx.z;
    const float* xd = x + (long)d * cL;
    float* xtd = xT + (long)d * cL;
    for (int o = threadIdx.x; o < 1024; o += 256) {
        int i = o >> 5, j = o & 31;
        t[i][j] = xd[(h0 + i) * 96 + w0 + j];
    }
    __syncthreads();
    for (int o = threadIdx.x; o < 1024; o += 256) {
        int i = o >> 5, j = o & 31;
        xtd[(w0 + i) * 96 + h0 + j] = t[j][i];
    }
}

// ---- kA: G = W_k @ src_k; delta[k][d][p], BC[k][36][256][32] ---------------
__global__ __launch_bounds__(256) void kA(const float* __restrict__ x,
                                          const float* __restrict__ xT,
                                          const float* __restrict__ xpw,
                                          const float* __restrict__ dtw,
                                          const float* __restrict__ dtb,
                                          float* __restrict__ delta,
                                          float* __restrict__ BC) {
    __shared__ float xs[96][64];
    __shared__ float xdbl[38][65];
    __shared__ float dtw_l[96 * 6];
    __shared__ float dtb_l[96];
    const int p0 = blockIdx.x * 64;
    const int k  = blockIdx.y;
    const int tid = threadIdx.x;
    const float* src = (k & 1) ? xT : x;

    for (int o = tid; o < 96 * 64; o += 256) {
        int dd = o >> 6, pp = o & 63;
        xs[dd][pp] = src[(long)dd * cL + p0 + pp];
    }
    for (int o = tid; o < 96 * 6; o += 256) dtw_l[o] = dtw[k * 96 * 6 + o];
    if (tid < 96) dtb_l[tid] = dtb[k * 96 + tid];
    __syncthreads();

    const int lane = tid & 63;
    const int c0 = __builtin_amdgcn_readfirstlane((tid >> 6) * 10);
    const float* wk = xpw + (long)k * 38 * 96;
    float acc[10];
    #pragma unroll
    for (int i = 0; i < 10; ++i) acc[i] = 0.f;
    #pragma unroll 4
    for (int dd = 0; dd < 96; ++dd) {
        float xv = xs[dd][lane];
        #pragma unroll
        for (int i = 0; i < 10; ++i) {
            int c = c0 + i; c = c > 37 ? 37 : c;
            acc[i] = fmaf(xv, wk[c * 96 + dd], acc[i]);
        }
    }
    #pragma unroll
    for (int i = 0; i < 10; ++i) {
        int c = c0 + i; c = c > 37 ? 37 : c;
        xdbl[c][lane] = acc[i];
    }
    __syncthreads();

    for (int o = tid; o < 64 * 16; o += 256) {
        int n = o & 15, pp = o >> 4;
        int P = p0 + pp;
        int q = (k < 2) ? P : (9215 - P);
        int ch = q / 36, j = q - ch * 36;
        long idx = (((long)k * 36 + j) * 256 + ch) * 32 + n;
        BC[idx]      = xdbl[6 + n][pp];
        BC[idx + 16] = xdbl[22 + n][pp];
    }
    for (int o = tid; o < 96 * 64; o += 256) {
        int dd = o >> 6, pp = o & 63;
        float s = dtb_l[dd];
        #pragma unroll
        for (int r = 0; r < 6; ++r) s = fmaf(xdbl[r][pp], dtw_l[dd * 6 + r], s);
        float sp = fmaxf(s, 0.f) + __logf(1.f + __expf(-fabsf(s)));
        delta[((long)(k * 96 + dd)) * cL + p0 + pp] = sp;
    }
}

// ---- kS1: half-seq summaries; delta/x staged in LDS ------------------------
__global__ __launch_bounds__(512, 6) void kS1(const float* __restrict__ x,
                                              const float* __restrict__ xT,
                                              const float* __restrict__ delta,
                                              const float* __restrict__ BC,
                                              const float* __restrict__ Alog,
                                              float* __restrict__ Pg,
                                              float* __restrict__ Sg) {
    __shared__ float dls[4608], xls[4608];      // 36.9 KB
    const int tid = threadIdx.x;
    const int n0 = (tid & 3) * 4, chl = tid >> 2;   // chl in [0,128)
    const int hb = blockIdx.x & 1, seq = blockIdx.x >> 1;
    const int k = seq / 96, d = seq % 96, rev = k >> 1;
    const int ch = hb * 128 + chl;

    const float* dRow = delta + (long)seq * cL;
    const float* xRow = ((k & 1) ? xT : x) + (long)d * cL;
    const int sb2 = rev ? (1 - hb) * 4608 : hb * 4608;   // spatial base of range
    for (int o = tid; o < 1152; o += 512) {
        ((float4*)dls)[o] = ((const float4*)(dRow + sb2))[o];
        ((float4*)xls)[o] = ((const float4*)(xRow + sb2))[o];
    }
    const float4 a2 = a2prep(*(const float4*)(Alog + (long)seq * 16 + n0));
    const float* bc = BC + ((long)k * 36 * 256 + ch) * 32 + n0;
    __syncthreads();

    const int sbase = chl * 36;                 // local scan base within half
    float4 h = make_float4(0.f, 0.f, 0.f, 0.f);
    float sdl = 0.f;
#define STEP1(DL, XV, B) { \
        float t = (DL) * (XV); sdl += (DL); \
        h.x = fmaf(exp2f((DL)*a2.x), h.x, t*(B).x); \
        h.y = fmaf(exp2f((DL)*a2.y), h.y, t*(B).y); \
        h.z = fmaf(exp2f((DL)*a2.z), h.z, t*(B).z); \
        h.w = fmaf(exp2f((DL)*a2.w), h.w, t*(B).w); }
    #pragma unroll
    for (int g = 0; g < 9; ++g) {
        const float* bj = bc + (long)(4 * g) * 8192;
        float4 B0 = *(const float4*)(bj);
        float4 B1 = *(const float4*)(bj + 8192);
        float4 B2 = *(const float4*)(bj + 16384);
        float4 B3 = *(const float4*)(bj + 24576);
        float4 d4, x4;
        if (!rev) {
            d4 = *(const float4*)(dls + sbase + 4 * g);
            x4 = *(const float4*)(xls + sbase + 4 * g);
            STEP1(d4.x, x4.x, B0) STEP1(d4.y, x4.y, B1)
            STEP1(d4.z, x4.z, B2) STEP1(d4.w, x4.w, B3)
        } else {
            d4 = *(const float4*)(dls + 4604 - sbase - 4 * g);
            x4 = *(const float4*)(xls + 4604 - sbase - 4 * g);
            STEP1(d4.w, x4.w, B0) STEP1(d4.z, x4.z, B1)
            STEP1(d4.y, x4.y, B2) STEP1(d4.x, x4.x, B3)
        }
    }
#undef STEP1
    long o = ((long)seq * NCH + ch) * 16 + n0;
    *(float4*)(Pg + o) = make_float4(exp2f(a2.x*sdl), exp2f(a2.y*sdl),
                                     exp2f(a2.z*sdl), exp2f(a2.w*sdl));
    *(float4*)(Sg + o) = h;
}

// ---- kC: scan 256 summaries per seq; exclusive inits overwrite Pg ----------
__global__ __launch_bounds__(256) void kC(float* __restrict__ Pg,
                                          const float* __restrict__ Sg) {
    __shared__ float gp[256], gs[256];
    const int seq = blockIdx.x;
    const int tid = threadIdx.x;
    const int sn = tid & 15, sg = tid >> 4;          // sg in [0,16)
    const long base = (long)seq * 4096 + sg * 256 + sn;

    float LPe[16], LSe[16];
    float P = 1.f, S = 0.f;
    #pragma unroll
    for (int i = 0; i < 16; ++i) {
        float p = Pg[base + i * 16], s = Sg[base + i * 16];
        LPe[i] = P; LSe[i] = S;
        S = fmaf(p, S, s); P *= p;
    }
    gp[tid] = P; gs[tid] = S;
    __syncthreads();
    #pragma unroll
    for (int off = 1; off < 16; off <<= 1) {
        float pc = gp[tid], sc = gs[tid];
        float pn = pc, s2 = sc;
        if (sg >= off) {
            pn = pc * gp[tid - off * 16];
            s2 = fmaf(pc, gs[tid - off * 16], sc);
        }
        __syncthreads();
        gp[tid] = pn; gs[tid] = s2;
        __syncthreads();
    }
    const float GS = (sg == 0) ? 0.f : gs[tid - 16];
    #pragma unroll
    for (int i = 0; i < 16; ++i)
        Pg[base + i * 16] = fmaf(LPe[i], GS, LSe[i]);  // hin
}

// ---- kR: pure replay, quarter-seq blocks; delta/x staged; ybuf writeout ----
__global__ __launch_bounds__(256, 5) void kR(const float* __restrict__ x,
                                             const float* __restrict__ xT,
                                             const float* __restrict__ delta,
                                             const float* __restrict__ BC,
                                             const float* __restrict__ Alog,
                                             const float* __restrict__ Dsv,
                                             const float* __restrict__ hin,
                                             float* __restrict__ y) {
    __shared__ float dls[2304], xls[2304];
    __shared__ float ybuf[2304 + 24];
    const int tid = threadIdx.x;
    const int n0 = (tid & 3) * 4, chl = tid >> 2, r = tid & 3;  // chl [0,64)
    const int qb = blockIdx.x & 3, seq = blockIdx.x >> 2;
    const int k = seq / 96, d = seq % 96, rev = k >> 1;
    const int ch = qb * 64 + chl;

    const float* dRow = delta + (long)seq * cL;
    const float* xRow = ((k & 1) ? xT : x) + (long)d * cL;
    const int sb = rev ? (3 - qb) * 2304 : qb * 2304;    // spatial base
    for (int o = tid; o < 576; o += 256) {
        ((float4*)dls)[o] = ((const float4*)(dRow + sb))[o];
        ((float4*)xls)[o] = ((const float4*)(xRow + sb))[o];
    }
    const float4 a2 = a2prep(*(const float4*)(Alog + (long)seq * 16 + n0));
    const float Dv = Dsv[seq];
    const float* bc = BC + ((long)k * 36 * 256 + ch) * 32 + n0;
    float4 h = *(const float4*)(hin + ((long)seq * NCH + ch) * 16 + n0);
    __syncthreads();

    const int sbase = chl * 36;
    float yhold = 0.f;
#define STEP2(DL, XV, B, C, SI) { \
        float t = (DL) * (XV); \
        h.x = fmaf(exp2f((DL)*a2.x), h.x, t*(B).x); \
        h.y = fmaf(exp2f((DL)*a2.y), h.y, t*(B).y); \
        h.z = fmaf(exp2f((DL)*a2.z), h.z, t*(B).z); \
        h.w = fmaf(exp2f((DL)*a2.w), h.w, t*(B).w); \
        float pv = fmaf(h.x, (C).x, fmaf(h.y, (C).y, fmaf(h.z, (C).z, h.w * (C).w))); \
        pv += qperm<0xB1>(pv); \
        pv += qperm<0x4E>(pv); \
        if ((SI) == r) yhold = fmaf(Dv, (XV), pv); }
    #pragma unroll
    for (int g = 0; g < 9; ++g) {
        const float* bj = bc + (long)(4 * g) * 8192;
        float4 B0 = *(const float4*)(bj);
        float4 C0 = *(const float4*)(bj + 16);
        float4 B1 = *(const float4*)(bj + 8192);
        float4 C1 = *(const float4*)(bj + 8192 + 16);
        float4 B2 = *(const float4*)(bj + 16384);
        float4 C2 = *(const float4*)(bj + 16384 + 16);
        float4 B3 = *(const float4*)(bj + 24576);
        float4 C3 = *(const float4*)(bj + 24576 + 16);
        float4 d4, x4;
        if (!rev) {
            d4 = *(const float4*)(dls + sbase + 4 * g);
            x4 = *(const float4*)(xls + sbase + 4 * g);
            STEP2(d4.x, x4.x, B0, C0, 0) STEP2(d4.y, x4.y, B1, C1, 1)
            STEP2(d4.z, x4.z, B2, C2, 2) STEP2(d4.w, x4.w, B3, C3, 3)
        } else {
            d4 = *(const float4*)(dls + 2300 - sbase - 4 * g);
            x4 = *(const float4*)(xls + 2300 - sbase - 4 * g);
            STEP2(d4.w, x4.w, B0, C0, 0) STEP2(d4.z, x4.z, B1, C1, 1)
            STEP2(d4.y, x4.y, B2, C2, 2) STEP2(d4.x, x4.x, B3, C3, 3)
        }
        int sl = sbase + 4 * g + r;
        int yloc = rev ? 2303 - sl : sl;
        ybuf[yloc + yloc / 96] = yhold;
    }
#undef STEP2
    __syncthreads();

    float* yrow = y + (long)seq * cL;
    if (k & 1) {
        const int w0 = sb / 96;
        for (int o = tid; o < 2304; o += 256) {
            int hh = o / 24, wl = o - hh * 24;
            yrow[hh * 96 + w0 + wl] = ybuf[wl * 97 + hh];
        }
    } else {
        for (int o = tid; o < 2304; o += 256) {
            yrow[sb + o] = ybuf[o + o / 96];
        }
    }
}

// ---- kE: 4-dir sum (all spatial, d-major) + LayerNorm; 32 p per block ------
__global__ __launch_bounds__(256) void kE(const float* __restrict__ y,
                                          const float* __restrict__ lnw,
                                          const float* __restrict__ lnb,
                                          float* __restrict__ out) {
    __shared__ float vs[96][36];
    __shared__ float red[8][32], red2[8][32];
    __shared__ float MU[32], RS[32];
    const int tid = threadIdx.x;
    const int p0 = blockIdx.x * 32;

    for (int o = tid; o < 96 * 8; o += 256) {
        int dd = o >> 3, j = o & 7;
        const float* r0 = y + (long)dd * cL + p0;
        const float* r1 = y + cDL + (long)dd * cL + p0;
        const float* r2 = y + 2 * cDL + (long)dd * cL + p0;
        const float* r3 = y + 3 * cDL + (long)dd * cL + p0;
        float4 a = ((const float4*)r0)[j];
        float4 b = ((const float4*)r1)[j];
        float4 c = ((const float4*)r2)[j];
        float4 e = ((const float4*)r3)[j];
        *(float4*)&vs[dd][4 * j] = make_float4(a.x + b.x + c.x + e.x,
                                               a.y + b.y + c.y + e.y,
                                               a.z + b.z + c.z + e.z,
                                               a.w + b.w + c.w + e.w);
    }
    __syncthreads();

    const int p = tid & 31, part = tid >> 5;
    float s = 0.f, s2 = 0.f;
    for (int dd = part * 12; dd < part * 12 + 12; ++dd) {
        float v = vs[dd][p];
        s += v; s2 = fmaf(v, v, s2);
    }
    red[part][p] = s; red2[part][p] = s2;
    __syncthreads();
    if (tid < 32) {
        float S = 0.f, S2 = 0.f;
        #pragma unroll
        for (int q = 0; q < 8; ++q) { S += red[q][tid]; S2 += red2[q][tid]; }
        float m = S * (1.f / 96.f);
        MU[tid] = m;
        RS[tid] = rsqrtf(S2 * (1.f / 96.f) - m * m + 1e-5f);
    }
    __syncthreads();
    for (int o = tid; o < 32 * 96; o += 256) {
        int pl = o / 96, dd = o - pl * 96;
        out[(long)(p0 + pl) * 96 + dd] = (vs[dd][pl] - MU[pl]) * RS[pl] * lnw[dd] + lnb[dd];
    }
}

extern "C" void kernel_launch(void* const* d_in, const int* in_sizes, int n_in,
                              void* d_out, int out_size, void* d_ws, size_t ws_size,
                              hipStream_t stream) {
    const float* x    = (const float*)d_in[0];
    const float* xpw  = (const float*)d_in[1];
    const float* dtw  = (const float*)d_in[2];
    const float* dtb  = (const float*)d_in[3];
    const float* Alog = (const float*)d_in[4];
    const float* Dsv  = (const float*)d_in[5];
    const float* lnw  = (const float*)d_in[6];
    const float* lnb  = (const float*)d_in[7];
    float* ws = (float*)d_ws;

    float* xT    = ws + OFF_XT;
    float* delta = ws + OFF_DELTA;
    float* BC    = ws + OFF_BC;
    float* y     = ws + OFF_Y;
    float* Pg    = ws + OFF_PG;     // -> hin after kC
    float* Sg    = ws + OFF_SG;
    float* out   = (float*)d_out;

    kT<<<dim3(3, 3, 96), 256, 0, stream>>>(x, xT);
    kA<<<dim3(144, 4), 256, 0, stream>>>(x, xT, xpw, dtw, dtb, delta, BC);
    kS1<<<768, 512, 0, stream>>>(x, xT, delta, BC, Alog, Pg, Sg);
    kC<<<384, 256, 0, stream>>>(Pg, Sg);
    kR<<<1536, 256, 0, stream>>>(x, xT, delta, BC, Alog, Dsv, Pg, y);
    kE<<<288, 256, 0, stream>>>(y, lnw, lnb, out);
}